// Round 3
// baseline (260.024 us; speedup 1.0000x reference)
//
#include <hip/hip_runtime.h>
#include <hip/hip_bf16.h>

#define NFP   10000
#define DIM   70
#define GPAD  72      // G row stride in u16 (and gTs row stride)
#define NATOMS 64

typedef short  short8  __attribute__((ext_vector_type(8)));
typedef float  floatx4 __attribute__((ext_vector_type(4)));

__device__ inline unsigned short f2bf(float f) {
  union { float f; unsigned u; } x; x.f = f;
  unsigned r = x.u + 0x7fffu + ((x.u >> 16) & 1u);
  return (unsigned short)(r >> 16);
}

__device__ inline ushort2 pk2bf(float a, float b) {
  __hip_bfloat162 h = __float22bfloat162_rn(make_float2(a, b));
  union { __hip_bfloat162 h; ushort2 u; } c; c.h = h; return c.u;
}

// G[v][72] (bf16, cols 70,71 = 0) = relu(emb[v] @ w1 + b1) @ w2
__global__ __launch_bounds__(256) void precompute_G(
    const float* __restrict__ emb, const float* __restrict__ w1,
    const float* __restrict__ b1,  const float* __restrict__ w2,
    unsigned short* __restrict__ G) {
  __shared__ float w1s[DIM * GPAD];
  __shared__ float w2s[DIM * GPAD];
  __shared__ float b1s[GPAD];
  __shared__ float embs[32 * GPAD];
  __shared__ float e1s[32 * GPAD];
  const int t = threadIdx.x;

  for (int i = t; i < DIM * GPAD; i += 256) {
    int r = i / GPAD, c = i % GPAD;
    float v1 = 0.f, v2 = 0.f;
    if (c < DIM) { v1 = w1[r * DIM + c]; v2 = w2[r * DIM + c]; }
    w1s[i] = v1; w2s[i] = v2;
  }
  if (t < GPAD) b1s[t] = (t < DIM) ? b1[t] : 0.f;
  const int row0 = blockIdx.x * 32;
  for (int i = t; i < 32 * GPAD; i += 256) {
    int r = i / GPAD, c = i % GPAD;
    int vr = row0 + r;
    embs[i] = (vr < NFP && c < DIM) ? emb[vr * DIM + c] : 0.f;
  }
  __syncthreads();

  for (int task = t; task < 32 * 18; task += 256) {
    int r = task / 18, c4 = (task % 18) * 4;
    float4 acc = *(const float4*)&b1s[c4];
    for (int k = 0; k < DIM; k++) {
      float e = embs[r * GPAD + k];
      float4 w = *(const float4*)&w1s[k * GPAD + c4];
      acc.x = fmaf(e, w.x, acc.x); acc.y = fmaf(e, w.y, acc.y);
      acc.z = fmaf(e, w.z, acc.z); acc.w = fmaf(e, w.w, acc.w);
    }
    acc.x = fmaxf(acc.x, 0.f); acc.y = fmaxf(acc.y, 0.f);
    acc.z = fmaxf(acc.z, 0.f); acc.w = fmaxf(acc.w, 0.f);
    *(float4*)&e1s[r * GPAD + c4] = acc;
  }
  __syncthreads();

  for (int task = t; task < 32 * 18; task += 256) {
    int r = task / 18, c4 = (task % 18) * 4;
    int vr = row0 + r;
    if (vr >= NFP) continue;
    float ax = 0.f, ay = 0.f, az = 0.f, aw = 0.f;
    for (int k = 0; k < DIM; k++) {
      float e = e1s[r * GPAD + k];
      float4 w = *(const float4*)&w2s[k * GPAD + c4];
      ax = fmaf(e, w.x, ax); ay = fmaf(e, w.y, ay);
      az = fmaf(e, w.z, az); aw = fmaf(e, w.w, aw);
    }
    unsigned short* gp = G + vr * GPAD + c4;
    gp[0] = f2bf(ax); gp[1] = f2bf(ay); gp[2] = f2bf(az); gp[3] = f2bf(aw);
  }
}

// One block per molecule. A-fragments (adjacency) straight from global into
// registers; G gathered+transposed into LDS; fused epilogue incl. projection.
__global__ __launch_bounds__(256, 6) void mol_fused(
    const int* __restrict__ atoms, const float* __restrict__ adj,
    const float* __restrict__ sel, const float* __restrict__ b2,
    const float* __restrict__ wp,  const float* __restrict__ bp,
    const unsigned short* __restrict__ G, float* __restrict__ out) {
  __shared__ unsigned short gTs[80 * GPAD];  // gT[d][m], bf16; rows 72..79 zero
  __shared__ float cpart[4 * 64];            // per-wave colsum partials
  __shared__ float b2p[80];
  __shared__ float wps[77 * 11];
  __shared__ float bps[11];
  __shared__ float yacc[4 * 80];
  __shared__ float yv[80];

  const int b = blockIdx.x;
  const int t = threadIdx.x;
  const int w = t >> 6, lane = t & 63;
  const int q = lane >> 4, li = lane & 15;
  const int R = w * 16;

  // --- A fragments direct from global; fp32 colsum partials via shuffles ---
  const float* rp = adj + (size_t)b * 4096 + (R + li) * 64;
  float4 v0 = *(const float4*)(rp + q * 8);
  float4 v1 = *(const float4*)(rp + q * 8 + 4);
  float4 v2 = *(const float4*)(rp + 32 + q * 8);
  float4 v3 = *(const float4*)(rp + 36 + q * 8);
  union { short8 s; ushort2 u[4]; } A0, A1;
  A0.u[0] = pk2bf(v0.x, v0.y); A0.u[1] = pk2bf(v0.z, v0.w);
  A0.u[2] = pk2bf(v1.x, v1.y); A0.u[3] = pk2bf(v1.z, v1.w);
  A1.u[0] = pk2bf(v2.x, v2.y); A1.u[1] = pk2bf(v2.z, v2.w);
  A1.u[2] = pk2bf(v3.x, v3.y); A1.u[3] = pk2bf(v3.z, v3.w);
  {
    float c[16] = {v0.x, v0.y, v0.z, v0.w, v1.x, v1.y, v1.z, v1.w,
                   v2.x, v2.y, v2.z, v2.w, v3.x, v3.y, v3.z, v3.w};
#pragma unroll
    for (int m = 1; m <= 8; m <<= 1)
#pragma unroll
      for (int i = 0; i < 16; i++) c[i] += __shfl_xor(c[i], m);
    if (li == 0) {
      float* cp = &cpart[w * 64];
      *(float4*)&cp[q * 8]      = make_float4(c[0], c[1], c[2], c[3]);
      *(float4*)&cp[q * 8 + 4]  = make_float4(c[4], c[5], c[6], c[7]);
      *(float4*)&cp[32 + q * 8]     = make_float4(c[8],  c[9],  c[10], c[11]);
      *(float4*)&cp[32 + q * 8 + 4] = make_float4(c[12], c[13], c[14], c[15]);
    }
  }

  // --- stage small weights ---
  for (int i = t; i < 77 * 11; i += 256) wps[i] = wp[i];
  if (t < 11) bps[t] = bp[t];
  if (t < 80) b2p[t] = (t < DIM) ? b2[t] : 0.f;

  // --- gather G rows pairwise, write transposed (ds_write_b32) ---
  {
    const uint4* Gv = (const uint4*)G;           // 9 uint4 per row
    const int p = t & 31;
    int2 aidx = *(const int2*)(atoms + b * 64 + 2 * p);
    int ch = t >> 5;                              // 0..7; ch=8 extra below
#pragma unroll
    for (int pass = 0; pass < 2; pass++) {
      if (pass == 1) { if (t >= 32) break; ch = 8; }
      uint4 g0 = Gv[(unsigned)aidx.x * 9 + ch];
      uint4 g1 = Gv[(unsigned)aidx.y * 9 + ch];
      unsigned base = (unsigned)(ch * 8) * GPAD + 2 * p;
      unsigned* d0 = (unsigned*)&gTs[base];
      d0[0 * (GPAD / 2) * 0] = 0;  // placeholder removed below
      *(unsigned*)&gTs[base + 0 * GPAD] = (g0.x & 0xffffu) | (g1.x << 16);
      *(unsigned*)&gTs[base + 1 * GPAD] = (g0.x >> 16) | (g1.x & 0xffff0000u);
      *(unsigned*)&gTs[base + 2 * GPAD] = (g0.y & 0xffffu) | (g1.y << 16);
      *(unsigned*)&gTs[base + 3 * GPAD] = (g0.y >> 16) | (g1.y & 0xffff0000u);
      *(unsigned*)&gTs[base + 4 * GPAD] = (g0.z & 0xffffu) | (g1.z << 16);
      *(unsigned*)&gTs[base + 5 * GPAD] = (g0.z >> 16) | (g1.z & 0xffff0000u);
      *(unsigned*)&gTs[base + 6 * GPAD] = (g0.w & 0xffffu) | (g1.w << 16);
      *(unsigned*)&gTs[base + 7 * GPAD] = (g0.w >> 16) | (g1.w & 0xffff0000u);
    }
  }
  // zero pad rows 72..79 (contiguous 1152 B)
  if (t < 72) {
    uint4 zz; zz.x = zz.y = zz.z = zz.w = 0u;
    *(uint4*)&gTs[72 * GPAD + t * 8] = zz;
  }
  __syncthreads();

  // --- column-sum weights for this lane's 4 output rows ---
  float cr[4];
#pragma unroll
  for (int r = 0; r < 4; r++) {
    int m = R + q * 4 + r;
    cr[r] = cpart[m] + cpart[64 + m] + cpart[128 + m] + cpart[192 + m];
  }

  // --- MFMA: h2pre[64][80] = adj @ g ---
  floatx4 acc[5];
#pragma unroll
  for (int nt = 0; nt < 5; nt++) {
    floatx4 z = {0.f, 0.f, 0.f, 0.f};
    short8 b0 = *(const short8*)&gTs[(nt * 16 + li) * GPAD + q * 8];
    short8 b1 = *(const short8*)&gTs[(nt * 16 + li) * GPAD + 32 + q * 8];
    z = __builtin_amdgcn_mfma_f32_16x16x32_bf16(A0.s, b0, z, 0, 0, 0);
    z = __builtin_amdgcn_mfma_f32_16x16x32_bf16(A1.s, b1, z, 0, 0, 0);
    acc[nt] = z;
  }

  // --- epilogue: y[d] = sum_m cvec[m] * relu(h2pre[m][d] + b2[d]) ---
  float ps[5];
#pragma unroll
  for (int nt = 0; nt < 5; nt++) {
    float bb = b2p[nt * 16 + li];
    float p = 0.f;
#pragma unroll
    for (int r = 0; r < 4; r++)
      p = fmaf(cr[r], fmaxf(acc[nt][r] + bb, 0.f), p);
    p += __shfl_xor(p, 16);
    p += __shfl_xor(p, 32);
    ps[nt] = p;
  }
  if (q == 0) {
#pragma unroll
    for (int nt = 0; nt < 5; nt++) yacc[w * 80 + nt * 16 + li] = ps[nt];
  }
  __syncthreads();

  if (t < 77) {
    float s;
    if (t < DIM) s = yacc[t] + yacc[80 + t] + yacc[160 + t] + yacc[240 + t];
    else         s = sel[(size_t)b * 7 + (t - DIM)];
    yv[t] = s;
  }
  __syncthreads();

  if (t < 11) {
    float s = bps[t];
#pragma unroll 7
    for (int d = 0; d < 77; d++) s = fmaf(yv[d], wps[d * 11 + t], s);
    out[(size_t)b * 11 + t] = s;
  }
}

extern "C" void kernel_launch(void* const* d_in, const int* in_sizes, int n_in,
                              void* d_out, int out_size, void* d_ws, size_t ws_size,
                              hipStream_t stream) {
  const int*   atoms = (const int*)d_in[0];
  const float* adj   = (const float*)d_in[1];
  const float* sel   = (const float*)d_in[2];
  const float* emb   = (const float*)d_in[3];
  const float* w1    = (const float*)d_in[4];
  const float* b1    = (const float*)d_in[5];
  const float* w2    = (const float*)d_in[6];
  const float* b2    = (const float*)d_in[7];
  const float* wp    = (const float*)d_in[8];
  const float* bp    = (const float*)d_in[9];

  const int B = in_sizes[0] / NATOMS;          // 8192
  unsigned short* G = (unsigned short*)d_ws;   // 10000*72 bf16 = 1.44 MB

  precompute_G<<<(NFP + 31) / 32, 256, 0, stream>>>(emb, w1, b1, w2, G);
  mol_fused<<<B, 256, 0, stream>>>(atoms, adj, sel, b2, wp, bp, G, (float*)d_out);
}

// Round 4
// 243.381 us; speedup vs baseline: 1.0684x; 1.0684x over previous
//
#include <hip/hip_runtime.h>
#include <hip/hip_bf16.h>

#define NFP    10000
#define DIM    70
#define GPAD   72      // row stride in u16 for G and gTs
#define NATOMS 64
#define PGROWS 16      // vocab rows per precompute block

typedef short  short8  __attribute__((ext_vector_type(8)));
typedef float  floatx4 __attribute__((ext_vector_type(4)));

__device__ inline unsigned short f2bf(float f) {
  union { float f; unsigned u; } x; x.f = f;
  unsigned r = x.u + 0x7fffu + ((x.u >> 16) & 1u);
  return (unsigned short)(r >> 16);
}

__device__ inline ushort2 pk2bf(float a, float b) {
  __hip_bfloat162 h = __float22bfloat162_rn(make_float2(a, b));
  union { __hip_bfloat162 h; ushort2 u; } c; c.h = h; return c.u;
}

// G[v][72] (bf16, cols 70,71 = 0) = relu(emb[v] @ w1 + b1) @ w2
// PGROWS vocab rows per block -> 625 blocks (was 313).
__global__ __launch_bounds__(256) void precompute_G(
    const float* __restrict__ emb, const float* __restrict__ w1,
    const float* __restrict__ b1,  const float* __restrict__ w2,
    unsigned short* __restrict__ G) {
  __shared__ float w1s[DIM * GPAD];
  __shared__ float w2s[DIM * GPAD];
  __shared__ float b1s[GPAD];
  __shared__ float embs[PGROWS * GPAD];
  __shared__ float e1s[PGROWS * GPAD];
  const int t = threadIdx.x;

  for (int i = t; i < DIM * GPAD; i += 256) {
    int r = i / GPAD, c = i % GPAD;
    float v1 = 0.f, v2 = 0.f;
    if (c < DIM) { v1 = w1[r * DIM + c]; v2 = w2[r * DIM + c]; }
    w1s[i] = v1; w2s[i] = v2;
  }
  if (t < GPAD) b1s[t] = (t < DIM) ? b1[t] : 0.f;
  const int row0 = blockIdx.x * PGROWS;
  for (int i = t; i < PGROWS * GPAD; i += 256) {
    int r = i / GPAD, c = i % GPAD;
    int vr = row0 + r;
    embs[i] = (vr < NFP && c < DIM) ? emb[vr * DIM + c] : 0.f;
  }
  __syncthreads();

  for (int task = t; task < PGROWS * 18; task += 256) {
    int r = task / 18, c4 = (task % 18) * 4;
    float4 acc = *(const float4*)&b1s[c4];
    for (int k = 0; k < DIM; k++) {
      float e = embs[r * GPAD + k];
      float4 w = *(const float4*)&w1s[k * GPAD + c4];
      acc.x = fmaf(e, w.x, acc.x); acc.y = fmaf(e, w.y, acc.y);
      acc.z = fmaf(e, w.z, acc.z); acc.w = fmaf(e, w.w, acc.w);
    }
    acc.x = fmaxf(acc.x, 0.f); acc.y = fmaxf(acc.y, 0.f);
    acc.z = fmaxf(acc.z, 0.f); acc.w = fmaxf(acc.w, 0.f);
    *(float4*)&e1s[r * GPAD + c4] = acc;
  }
  __syncthreads();

  for (int task = t; task < PGROWS * 18; task += 256) {
    int r = task / 18, c4 = (task % 18) * 4;
    int vr = row0 + r;
    if (vr >= NFP) continue;
    float ax = 0.f, ay = 0.f, az = 0.f, aw = 0.f;
    for (int k = 0; k < DIM; k++) {
      float e = e1s[r * GPAD + k];
      float4 w = *(const float4*)&w2s[k * GPAD + c4];
      ax = fmaf(e, w.x, ax); ay = fmaf(e, w.y, ay);
      az = fmaf(e, w.z, az); aw = fmaf(e, w.w, aw);
    }
    unsigned short* gp = G + vr * GPAD + c4;
    gp[0] = f2bf(ax); gp[1] = f2bf(ay); gp[2] = f2bf(az); gp[3] = f2bf(aw);
  }
}

// One block per molecule: y = colsum(adj) @ relu(adj @ G[atoms] + b2);
// out = [y, sel] @ wp + bp, all fused.
__global__ __launch_bounds__(256) void mol_fused(
    const int* __restrict__ atoms, const float* __restrict__ adj,
    const float* __restrict__ sel, const float* __restrict__ b2,
    const float* __restrict__ wp,  const float* __restrict__ bp,
    const unsigned short* __restrict__ G, float* __restrict__ out) {
  __shared__ unsigned short adjs[64 * GPAD];   // adj bf16, pad 72
  __shared__ unsigned short gTs[80 * GPAD];    // gT[d][m] bf16; rows 72..79 zero
  __shared__ float cwave[4 * 64];              // per-wave colsum partials
  __shared__ float b2p[80];
  __shared__ float yacc[4 * 80];
  __shared__ float yv[80];
  __shared__ int   satoms[64];

  const int b = blockIdx.x;
  const int t = threadIdx.x;
  const int w = t >> 6, lane = t & 63;
  const int q = lane >> 4, li = lane & 15;
  const int R = w * 16;

  if (t < 64) satoms[t] = atoms[b * 64 + t];
  if (t < 80) b2p[t] = (t < DIM) ? b2[t] : 0.f;
  __syncthreads();

  // --- Stage adjacency fp32 -> bf16 LDS (coalesced full rows); colsum via shuffle ---
  {
    const float* ap = adj + (size_t)b * 4096;
    const int mc = (t & 15) * 4;
    const int a  = t >> 4;
    float4 cs = make_float4(0.f, 0.f, 0.f, 0.f);
#pragma unroll
    for (int it = 0; it < 4; it++) {
      int n = a + 16 * it;
      float4 v = *(const float4*)(ap + n * 64 + mc);
      cs.x += v.x; cs.y += v.y; cs.z += v.z; cs.w += v.w;
      ushort2 lo = pk2bf(v.x, v.y);
      ushort2 hi = pk2bf(v.z, v.w);
      ushort4 u; u.x = lo.x; u.y = lo.y; u.z = hi.x; u.w = hi.y;
      *(ushort4*)&adjs[n * GPAD + mc] = u;
    }
#pragma unroll
    for (int s = 16; s <= 32; s <<= 1) {
      cs.x += __shfl_xor(cs.x, s); cs.y += __shfl_xor(cs.y, s);
      cs.z += __shfl_xor(cs.z, s); cs.w += __shfl_xor(cs.w, s);
    }
    if (((t >> 4) & 3) == 0) *(float4*)&cwave[w * 64 + mc] = cs;
  }

  // --- Gather G[atoms] rows (uint4) and transpose into gT[d][m] ---
  {
    const int m = t & 63;
    const int row = satoms[m];
    const uint4* Gv = (const uint4*)G;   // 9 uint4 per 72-u16 row
    for (int ch = w; ch < 9; ch += 4) {
      uint4 v = Gv[(unsigned)row * 9 + ch];
      unsigned short* gp = &gTs[(ch * 8) * GPAD + m];
      gp[0 * GPAD] = (unsigned short)(v.x & 0xffff);
      gp[1 * GPAD] = (unsigned short)(v.x >> 16);
      gp[2 * GPAD] = (unsigned short)(v.y & 0xffff);
      gp[3 * GPAD] = (unsigned short)(v.y >> 16);
      gp[4 * GPAD] = (unsigned short)(v.z & 0xffff);
      gp[5 * GPAD] = (unsigned short)(v.z >> 16);
      gp[6 * GPAD] = (unsigned short)(v.w & 0xffff);
      gp[7 * GPAD] = (unsigned short)(v.w >> 16);
    }
  }
  // zero pad rows 72..79 (1152 contiguous bytes)
  if (t < 72) {
    uint4 zz; zz.x = zz.y = zz.z = zz.w = 0u;
    *(uint4*)&gTs[72 * GPAD + t * 8] = zz;
  }
  __syncthreads();

  // --- per-lane colsum weights for its 4 output rows (exact fp32) ---
  float cr[4];
#pragma unroll
  for (int r = 0; r < 4; r++) {
    int m = R + q * 4 + r;
    cr[r] = cwave[m] + cwave[64 + m] + cwave[128 + m] + cwave[192 + m];
  }

  // --- MFMA: h2pre[64][80] = adj @ g; wave w owns rows 16w..16w+15 ---
  short8 a0 = *(const short8*)&adjs[(R + li) * GPAD + q * 8];
  short8 a1 = *(const short8*)&adjs[(R + li) * GPAD + 32 + q * 8];
  floatx4 acc[5];
#pragma unroll
  for (int nt = 0; nt < 5; nt++) {
    floatx4 z = {0.f, 0.f, 0.f, 0.f};
    short8 b0 = *(const short8*)&gTs[(nt * 16 + li) * GPAD + q * 8];
    short8 b1 = *(const short8*)&gTs[(nt * 16 + li) * GPAD + 32 + q * 8];
    z = __builtin_amdgcn_mfma_f32_16x16x32_bf16(a0, b0, z, 0, 0, 0);
    z = __builtin_amdgcn_mfma_f32_16x16x32_bf16(a1, b1, z, 0, 0, 0);
    acc[nt] = z;
  }

  // --- epilogue: y[d] = sum_m cvec[m] * relu(h2pre[m][d] + b2[d]) ---
  float ps[5];
#pragma unroll
  for (int nt = 0; nt < 5; nt++) {
    float bb = b2p[nt * 16 + li];
    float p = 0.f;
#pragma unroll
    for (int r = 0; r < 4; r++)
      p = fmaf(cr[r], fmaxf(acc[nt][r] + bb, 0.f), p);
    p += __shfl_xor(p, 16);
    p += __shfl_xor(p, 32);
    ps[nt] = p;
  }
  if (q == 0) {
#pragma unroll
    for (int nt = 0; nt < 5; nt++) yacc[w * 80 + nt * 16 + li] = ps[nt];
  }
  __syncthreads();

  if (t < 77) {
    float s;
    if (t < DIM) s = yacc[t] + yacc[80 + t] + yacc[160 + t] + yacc[240 + t];
    else         s = sel[(size_t)b * 7 + (t - DIM)];
    yv[t] = s;
  }
  __syncthreads();

  // final projection: 11 lanes, wp/bp from L2 (tail overlaps across blocks)
  if (t < 11) {
    float s = bp[t];
#pragma unroll 11
    for (int d = 0; d < 77; d++) s = fmaf(yv[d], wp[d * 11 + t], s);
    out[(size_t)b * 11 + t] = s;
  }
}

extern "C" void kernel_launch(void* const* d_in, const int* in_sizes, int n_in,
                              void* d_out, int out_size, void* d_ws, size_t ws_size,
                              hipStream_t stream) {
  const int*   atoms = (const int*)d_in[0];
  const float* adj   = (const float*)d_in[1];
  const float* sel   = (const float*)d_in[2];
  const float* emb   = (const float*)d_in[3];
  const float* w1    = (const float*)d_in[4];
  const float* b1    = (const float*)d_in[5];
  const float* w2    = (const float*)d_in[6];
  const float* b2    = (const float*)d_in[7];
  const float* wp    = (const float*)d_in[8];
  const float* bp    = (const float*)d_in[9];

  const int B = in_sizes[0] / NATOMS;          // 8192
  unsigned short* G = (unsigned short*)d_ws;   // 10000*72 bf16 = 1.44 MB

  precompute_G<<<(NFP + PGROWS - 1) / PGROWS, 256, 0, stream>>>(emb, w1, b1, w2, G);
  mol_fused<<<B, 256, 0, stream>>>(atoms, adj, sel, b2, wp, bp, G, (float*)d_out);
}